// Round 1
// baseline (2431.587 us; speedup 1.0000x reference)
//
#include <hip/hip_runtime.h>
#include <stdint.h>

// SelfAttention: B=64,N=8,L=128,E=768,H=12,T=64  (S = B*N = 512 sets)
//
// Pipeline (all matmul in bf16 MFMA, fp32 accum):
//   Xb  = bf16(x)                        [65536,768]
//   P   = Xb @ (Wv * rsqrt(E))^T         [65536,768]  (cols = h*64+t)
//   per h: Qh = Xb @ Wq[h]^T + bq[h]     [65536,768]
//          fused: scores = Qh[s]@Xb[s]^T ; V' = scores@P[h,s] -> cat cols h*64..
//   out = cat @ Wf^T + (bf + Wf@bv)      [65536,768] fp32
//
// Workspace layout (needs ~420 MB):
//   Xb 0 .. 100663296, Pall .. 201326592, Qh .. 301989888, Cat .. 402653184,
//   Wqb .. 416808960, Wvb .. 417988608, Wfb .. 419168256, cv .. 419171328

#define EE 768
#define MROWS 65536

typedef short s16x8 __attribute__((ext_vector_type(8)));
typedef float f32x4 __attribute__((ext_vector_type(4)));

__device__ __forceinline__ short f2bf(float f){
  union { float fv; uint32_t u; } v; v.fv = f;
  uint32_t r = (v.u + 0x7fffu + ((v.u >> 16) & 1u)) >> 16;  // RNE
  return (short)r;
}

__device__ __forceinline__ void gld_lds16(const void* g, void* l){
  __builtin_amdgcn_global_load_lds(
      (const __attribute__((address_space(1))) void*)(uintptr_t)g,
      (__attribute__((address_space(3))) void*)(uintptr_t)l,
      16, 0, 0);
}

// ---------------- elementwise cast fp32 -> bf16 (with scale) ----------------
__global__ __launch_bounds__(256) void cast_bf16_k(const float* __restrict__ src,
                                                   short* __restrict__ dst,
                                                   long n, float scale){
  long i = ((long)blockIdx.x * 256 + threadIdx.x) * 8;
  if(i >= n) return;
  float4 a = *(const float4*)(src + i);
  float4 b = *(const float4*)(src + i + 4);
  s16x8 o;
  o[0] = f2bf(a.x * scale); o[1] = f2bf(a.y * scale);
  o[2] = f2bf(a.z * scale); o[3] = f2bf(a.w * scale);
  o[4] = f2bf(b.x * scale); o[5] = f2bf(b.y * scale);
  o[6] = f2bf(b.z * scale); o[7] = f2bf(b.w * scale);
  *(s16x8*)(dst + i) = o;
}

// ---------------- c[e] = bf[e] + sum_k Wf[e,k] * bv[k] ----------------------
__global__ __launch_bounds__(256) void cvec_k(const float* __restrict__ Wf,
                                              const float* __restrict__ bv,
                                              const float* __restrict__ bfv,
                                              float* __restrict__ c){
  int e = blockIdx.x * 256 + threadIdx.x;
  if(e >= EE) return;
  float s = bfv[e];
  for(int k = 0; k < EE; ++k) s += Wf[(long)e * EE + k] * bv[k];
  c[e] = s;
}

// ------ C[M,N] = A[M,K] @ B[N,K]^T (+ bias[col]); A,B bf16 row-major --------
// m97 structure: 128x128 tile, 4 waves (2x2), BK=64, global_load_lds w=16.
template<bool OUTF32>
__global__ __launch_bounds__(256) void gemm_bt(const short* __restrict__ A,
                                               const short* __restrict__ B,
                                               const float* __restrict__ bias,
                                               void* __restrict__ Cout,
                                               int M, int N, int K){
  __shared__ short As[128][64];
  __shared__ short Bs[128][64];
  const int tid = threadIdx.x, lane = tid & 63, w = tid >> 6;
  const int wr = w >> 1, wc = w & 1;
  const long rowA0 = (long)blockIdx.y * 128;
  const long colB0 = (long)blockIdx.x * 128;
  const int lr = lane >> 3, lc = (lane & 7) * 8;

  f32x4 acc[4][4] = {};

  for(int kt = 0; kt < K; kt += 64){
    __syncthreads();
    #pragma unroll
    for(int it = 0; it < 4; ++it){
      int r = it * 32 + w * 8;
      gld_lds16(&A[(rowA0 + r + lr) * K + kt + lc], &As[r][0]);
      gld_lds16(&B[(colB0 + r + lr) * K + kt + lc], &Bs[r][0]);
    }
    __syncthreads();
    #pragma unroll
    for(int kk = 0; kk < 2; ++kk){
      s16x8 af[4], bfr[4];
      #pragma unroll
      for(int m = 0; m < 4; ++m)
        af[m] = *(const s16x8*)&As[wr*64 + m*16 + (lane & 15)][kk*32 + (lane >> 4)*8];
      #pragma unroll
      for(int n = 0; n < 4; ++n)
        bfr[n] = *(const s16x8*)&Bs[wc*64 + n*16 + (lane & 15)][kk*32 + (lane >> 4)*8];
      #pragma unroll
      for(int m = 0; m < 4; ++m)
        #pragma unroll
        for(int n = 0; n < 4; ++n)
          acc[m][n] = __builtin_amdgcn_mfma_f32_16x16x32_bf16(af[m], bfr[n], acc[m][n], 0, 0, 0);
    }
  }

  // C/D layout: col = lane&15, row = (lane>>4)*4 + r  [m89/m91 verified]
  const long crow0 = rowA0 + wr * 64;
  const long ccol0 = colB0 + wc * 64;
  #pragma unroll
  for(int n = 0; n < 4; ++n){
    const long col = ccol0 + n*16 + (lane & 15);
    const float bb = bias ? bias[col] : 0.f;
    #pragma unroll
    for(int m = 0; m < 4; ++m){
      #pragma unroll
      for(int r = 0; r < 4; ++r){
        const long row = crow0 + m*16 + (lane >> 4)*4 + r;
        const float v = acc[m][n][r] + bb;
        if constexpr(OUTF32) ((float*)Cout)[row * N + col] = v;
        else                 ((short*)Cout)[row * N + col] = f2bf(v);
      }
    }
  }
}

// ------ fused per-(h,s): scores = Qh[s]@Xb[s]^T ; V' = scores@P ; -> cat ----
__global__ __launch_bounds__(256) void attn_fused(const short* __restrict__ Qh,
                                                  const short* __restrict__ Xb,
                                                  const short* __restrict__ Pall,
                                                  short* __restrict__ Cat,
                                                  int h){
  __shared__ short As[128][64];
  __shared__ short Bs[128][64];
  __shared__ short Ss[128][128];   // scores (bf16)
  __shared__ short Pt[64][128];    // P tile transposed: Pt[t][m] = P[m][t]
  const int tid = threadIdx.x, lane = tid & 63, w = tid >> 6;
  const int wr = w >> 1, wc = w & 1;
  const long row0 = (long)blockIdx.x * 128;   // s*128
  const int lr = lane >> 3, lc = (lane & 7) * 8;

  // phase 0: stage P tile (rows row0.., cols h*64..) transposed via registers
  {
    const int pl = tid >> 3;            // 0..31
    const int pt0 = (tid & 7) * 8;      // t segment
    #pragma unroll
    for(int i = 0; i < 4; ++i){
      const int m = pl + i * 32;
      s16x8 v = *(const s16x8*)&Pall[(row0 + m) * EE + h * 64 + pt0];
      #pragma unroll
      for(int j = 0; j < 8; ++j) Pt[pt0 + j][m] = v[j];
    }
  }

  // phase 1: scores[l][m] = sum_f Qh[row0+l][f] * Xb[row0+m][f]   (K=768)
  f32x4 accs[4][4] = {};
  for(int kt = 0; kt < EE; kt += 64){
    __syncthreads();
    #pragma unroll
    for(int it = 0; it < 4; ++it){
      int r = it * 32 + w * 8;
      gld_lds16(&Qh[(row0 + r + lr) * EE + kt + lc], &As[r][0]);
      gld_lds16(&Xb[(row0 + r + lr) * EE + kt + lc], &Bs[r][0]);
    }
    __syncthreads();
    #pragma unroll
    for(int kk = 0; kk < 2; ++kk){
      s16x8 af[4], bfr[4];
      #pragma unroll
      for(int m = 0; m < 4; ++m)
        af[m] = *(const s16x8*)&As[wr*64 + m*16 + (lane & 15)][kk*32 + (lane >> 4)*8];
      #pragma unroll
      for(int n = 0; n < 4; ++n)
        bfr[n] = *(const s16x8*)&Bs[wc*64 + n*16 + (lane & 15)][kk*32 + (lane >> 4)*8];
      #pragma unroll
      for(int m = 0; m < 4; ++m)
        #pragma unroll
        for(int n = 0; n < 4; ++n)
          accs[m][n] = __builtin_amdgcn_mfma_f32_16x16x32_bf16(af[m], bfr[n], accs[m][n], 0, 0, 0);
    }
  }

  // phase 2: scores -> Ss (bf16)
  #pragma unroll
  for(int m = 0; m < 4; ++m)
    #pragma unroll
    for(int n = 0; n < 4; ++n)
      #pragma unroll
      for(int r = 0; r < 4; ++r)
        Ss[wr*64 + m*16 + (lane >> 4)*4 + r][wc*64 + n*16 + (lane & 15)] = f2bf(accs[m][n][r]);
  __syncthreads();

  // phase 3: V'[l][t] = sum_m Ss[l][m] * P[m][t]   (M=128, N=64, K=128)
  // wave w owns rows w*32..w*32+31
  f32x4 accv[2][4] = {};
  #pragma unroll
  for(int kk = 0; kk < 4; ++kk){
    s16x8 a2[2], b4[4];
    #pragma unroll
    for(int m = 0; m < 2; ++m)
      a2[m] = *(const s16x8*)&Ss[w*32 + m*16 + (lane & 15)][kk*32 + (lane >> 4)*8];
    #pragma unroll
    for(int n = 0; n < 4; ++n)
      b4[n] = *(const s16x8*)&Pt[n*16 + (lane & 15)][kk*32 + (lane >> 4)*8];
    #pragma unroll
    for(int m = 0; m < 2; ++m)
      #pragma unroll
      for(int n = 0; n < 4; ++n)
        accv[m][n] = __builtin_amdgcn_mfma_f32_16x16x32_bf16(a2[m], b4[n], accv[m][n], 0, 0, 0);
  }

  // phase 4: write V' into cat columns h*64..h*64+63
  #pragma unroll
  for(int m = 0; m < 2; ++m)
    #pragma unroll
    for(int n = 0; n < 4; ++n)
      #pragma unroll
      for(int r = 0; r < 4; ++r){
        const long row = row0 + w*32 + m*16 + (lane >> 4)*4 + r;
        const int col = h*64 + n*16 + (lane & 15);
        Cat[row * EE + col] = f2bf(accv[m][n][r]);
      }
}

extern "C" void kernel_launch(void* const* d_in, const int* in_sizes, int n_in,
                              void* d_out, int out_size, void* d_ws, size_t ws_size,
                              hipStream_t stream){
  const float* x  = (const float*)d_in[0];  // [512*128, 768]
  const float* Wq = (const float*)d_in[1];  // [12,768,768]
  const float* bq = (const float*)d_in[2];  // [12,768]
  const float* Wv = (const float*)d_in[3];  // [12,64,768] -> flat [768,768]
  const float* bv = (const float*)d_in[4];  // [768]
  const float* Wf = (const float*)d_in[5];  // [768,768]
  const float* bfv= (const float*)d_in[6];  // [768]

  char* ws = (char*)d_ws;
  short* Xb   = (short*)(ws + 0L);
  short* Pall = (short*)(ws + 100663296L);
  short* Qh   = (short*)(ws + 201326592L);
  short* Cat  = (short*)(ws + 301989888L);
  short* Wqb  = (short*)(ws + 402653184L);
  short* Wvb  = (short*)(ws + 416808960L);
  short* Wfb  = (short*)(ws + 417988608L);
  float* cv   = (float*)(ws + 419168256L);

  const float rsqE = 0.03608439182435161f;  // 1/sqrt(768)

  cast_bf16_k<<<24576, 256, 0, stream>>>(x,  Xb,  50331648L, 1.f);
  cast_bf16_k<<<3456,  256, 0, stream>>>(Wq, Wqb, 7077888L,  1.f);
  cast_bf16_k<<<288,   256, 0, stream>>>(Wv, Wvb, 589824L,   rsqE);
  cast_bf16_k<<<288,   256, 0, stream>>>(Wf, Wfb, 589824L,   1.f);
  cvec_k<<<3, 256, 0, stream>>>(Wf, bv, bfv, cv);

  dim3 g6(6, 512), b256(256);
  // P = Xb @ (Wv*rsqE)^T
  gemm_bt<false><<<g6, b256, 0, stream>>>(Xb, Wvb, nullptr, Pall, MROWS, EE, EE);

  for(int h = 0; h < 12; ++h){
    gemm_bt<false><<<g6, b256, 0, stream>>>(Xb, Wqb + (long)h * 589824L,
                                            bq + h * 768, Qh, MROWS, EE, EE);
    attn_fused<<<dim3(512), b256, 0, stream>>>(Qh, Xb, Pall, Cat, h);
  }

  // out = Cat @ Wf^T + cv   (fp32 out)
  gemm_bt<true><<<g6, b256, 0, stream>>>(Cat, Wfb, cv, d_out, MROWS, EE, EE);
}

// Round 2
// 1856.920 us; speedup vs baseline: 1.3095x; 1.3095x over previous
//
#include <hip/hip_runtime.h>
#include <stdint.h>

// SelfAttention: B=64,N=8,L=128,E=768,H=12,T=64  (S=512 sets of 128 tokens)
//
// Pipeline (bf16 MFMA, fp32 accum):
//   Xb = bf16(x)                                  [65536,768]
//   QP = Xb @ [Wq_all ; Wv*rsqrt(E)]^T + [bq;0]   [65536,9984]  (one GEMM)
//   attn per (h,s): scores = Q[h,s]@Xs^T ; V' = scores@P[h,s] -> Cat cols h*64..
//   out = Cat @ Wf^T + (bf + Wf@bv)               [65536,768] fp32
//
// GEMM: 128x128 tile, 4 waves, BK=64, double-buffered LDS with counted
// vmcnt(8) (T3/T4-lite), XOR-swizzled LDS (T2, both-sides per rule #21),
// XCD-chunked + GROUP_M=8 grid (T1), LDS-routed coalesced bf16 epilogue.

#define EE 768

typedef short s16x8 __attribute__((ext_vector_type(8)));
typedef float f32x4 __attribute__((ext_vector_type(4)));

__device__ __forceinline__ short f2bf(float f){
  union { float fv; uint32_t u; } v; v.fv = f;
  uint32_t r = (v.u + 0x7fffu + ((v.u >> 16) & 1u)) >> 16;  // RNE
  return (short)r;
}

__device__ __forceinline__ void gld_lds16(const short* g, short* l){
  __builtin_amdgcn_global_load_lds(
      (const __attribute__((address_space(1))) void*)(uintptr_t)g,
      (__attribute__((address_space(3))) void*)(uintptr_t)l,
      16, 0, 0);
}

// bijective XCD chunking (m204): consecutive logical ids land on one XCD
__device__ __forceinline__ int xcd_swz(int bid, int nwg){
  int xcd = bid & 7, loc = bid >> 3;
  int q = nwg >> 3, r = nwg & 7;
  return (xcd < r ? xcd * (q + 1) : r * (q + 1) + (xcd - r) * q) + loc;
}

// LDS bank-conflict swizzle (involution, applied at stage-src AND read)
__device__ __forceinline__ int swz(int row, int colShort){
  return colShort ^ ((row & 7) << 3);
}

// ---------------- casts / small helpers ----------------
__global__ __launch_bounds__(256) void cast_bf16_k(const float* __restrict__ src,
                                                   short* __restrict__ dst,
                                                   long n, float scale){
  long i = ((long)blockIdx.x * 256 + threadIdx.x) * 8;
  if(i >= n) return;
  float4 a = *(const float4*)(src + i);
  float4 b = *(const float4*)(src + i + 4);
  s16x8 o;
  o[0]=f2bf(a.x*scale); o[1]=f2bf(a.y*scale); o[2]=f2bf(a.z*scale); o[3]=f2bf(a.w*scale);
  o[4]=f2bf(b.x*scale); o[5]=f2bf(b.y*scale); o[6]=f2bf(b.z*scale); o[7]=f2bf(b.w*scale);
  *(s16x8*)(dst + i) = o;
}

__global__ __launch_bounds__(256) void cvec_k(const float* __restrict__ Wf,
                                              const float* __restrict__ bv,
                                              const float* __restrict__ bfv,
                                              float* __restrict__ c){
  int e = blockIdx.x * 256 + threadIdx.x;
  if(e >= EE) return;
  float s = bfv[e];
  for(int k = 0; k < EE; ++k) s += Wf[(long)e * EE + k] * bv[k];
  c[e] = s;
}

__global__ __launch_bounds__(256) void bias_build(const float* __restrict__ bq,
                                                  float* __restrict__ biasQP){
  int i = blockIdx.x * 256 + threadIdx.x;
  if(i < 9984) biasQP[i] = (i < 9216) ? bq[i] : 0.f;
}

// ------ C[M,N] = A[M,K] @ B[N,K]^T (+ bias[col]); M must be 65536 -----------
template<bool OUTF32>
__global__ __launch_bounds__(256, 2) void gemm_bt(const short* __restrict__ A,
                                                  const short* __restrict__ B,
                                                  const float* __restrict__ bias,
                                                  void* __restrict__ Cout,
                                                  int N, int K){
  __shared__ short smem[4 * 8192];  // As0|Bs0|As1|Bs1 (16KB each), 64KB total
  const int tid = threadIdx.x, lane = tid & 63, w = tid >> 6;
  const int wr = w >> 1, wc = w & 1;
  // grid: 512*(N/128) blocks; per-XCD chunk = 64 row-panels; GROUP_M=8
  const int nCol = N >> 7;
  const int xcd = blockIdx.x & 7, loc = blockIdx.x >> 3;
  const int width = nCol << 3;
  const int gid = loc / width, rem = loc % width;
  const int rowBlk = (xcd << 6) + (gid << 3) + (rem & 7);
  const int colBlk = rem >> 3;
  const long rowA0 = (long)rowBlk << 7;
  const long colB0 = (long)colBlk << 7;
  const int lr = lane >> 3;
  const int sA = swz(lr, (lane & 7) * 8);  // pre-swizzled source column

  f32x4 acc[4][4] = {};
  const int NT = K >> 6;

  auto stage = [&](int b, int kt){
    short* As = smem + b * 16384;
    #pragma unroll
    for(int it = 0; it < 4; ++it){
      int r = it * 32 + w * 8;
      gld_lds16(&A[(rowA0 + r + lr) * K + kt + sA], &As[r * 64]);
      gld_lds16(&B[(colB0 + r + lr) * K + kt + sA], &As[8192 + r * 64]);
    }
  };

  stage(0, 0);
  for(int t = 0; t < NT; ++t){
    const int cur = t & 1;
    if(t + 1 < NT){
      stage(cur ^ 1, (t + 1) * 64);
      asm volatile("s_waitcnt vmcnt(8)\n\ts_barrier" ::: "memory");
    } else {
      asm volatile("s_waitcnt vmcnt(0)\n\ts_barrier" ::: "memory");
    }
    const short* As = smem + cur * 16384;
    const short* Bs = As + 8192;
    #pragma unroll
    for(int kk = 0; kk < 2; ++kk){
      s16x8 af[4], bfr[4];
      #pragma unroll
      for(int m = 0; m < 4; ++m){
        int row = wr * 64 + m * 16 + (lane & 15);
        af[m] = *(const s16x8*)&As[row * 64 + swz(row, kk * 32 + (lane >> 4) * 8)];
      }
      #pragma unroll
      for(int n = 0; n < 4; ++n){
        int row = wc * 64 + n * 16 + (lane & 15);
        bfr[n] = *(const s16x8*)&Bs[row * 64 + swz(row, kk * 32 + (lane >> 4) * 8)];
      }
      #pragma unroll
      for(int m = 0; m < 4; ++m)
        #pragma unroll
        for(int n = 0; n < 4; ++n)
          acc[m][n] = __builtin_amdgcn_mfma_f32_16x16x32_bf16(af[m], bfr[n], acc[m][n], 0, 0, 0);
    }
    asm volatile("s_barrier" ::: "memory");
  }

  if constexpr(!OUTF32){
    // LDS-routed coalesced epilogue: Cs overlays smem (staging is dead)
    short* Cs = smem;  // [128][128]
    #pragma unroll
    for(int n = 0; n < 4; ++n){
      const long col = colB0 + wc * 64 + n * 16 + (lane & 15);
      const float bb = bias ? bias[col] : 0.f;
      #pragma unroll
      for(int m = 0; m < 4; ++m)
        #pragma unroll
        for(int r = 0; r < 4; ++r){
          int row = wr * 64 + m * 16 + (lane >> 4) * 4 + r;
          int c = wc * 64 + n * 16 + (lane & 15);
          Cs[row * 128 + (c ^ ((row & 7) * 8))] = f2bf(acc[m][n][r] + bb);
        }
    }
    __syncthreads();
    short* Co = (short*)Cout;
    #pragma unroll
    for(int k2 = 0; k2 < 8; ++k2){
      int row = k2 * 16 + (tid >> 4);
      int cl = (tid & 15) * 8;                    // logical col (shorts)
      s16x8 v = *(const s16x8*)&Cs[row * 128 + (cl ^ ((row & 7) * 8))];
      *(s16x8*)&Co[(rowA0 + row) * N + colB0 + cl] = v;
    }
  } else {
    float* Co = (float*)Cout;
    const long crow0 = rowA0 + wr * 64;
    const long ccol0 = colB0 + wc * 64;
    #pragma unroll
    for(int n = 0; n < 4; ++n){
      const long col = ccol0 + n * 16 + (lane & 15);
      const float bb = bias ? bias[col] : 0.f;
      #pragma unroll
      for(int m = 0; m < 4; ++m)
        #pragma unroll
        for(int r = 0; r < 4; ++r){
          const long row = crow0 + m * 16 + (lane >> 4) * 4 + r;
          Co[row * N + col] = acc[m][n][r] + bb;
        }
    }
  }
}

// ------ fused per-(h,s): scores = Q@Xs^T ; V' = scores@P ; -> Cat -----------
__global__ __launch_bounds__(256, 2) void attn_k(const short* __restrict__ Q, int QS,
                                                 const short* __restrict__ P, int PS,
                                                 const short* __restrict__ X,
                                                 short* __restrict__ Cat,
                                                 int h0, int nH){
  __shared__ short smem[4 * 8192];  // 64KB; staging dbuf, later overlaid
  const int tid = threadIdx.x, lane = tid & 63, w = tid >> 6;
  const int wr = w >> 1, wc = w & 1;
  const int nwg = nH << 9;
  const int bid = xcd_swz(blockIdx.x, nwg);
  const int s = bid / nH, hi = bid - s * nH, h = h0 + hi;
  const long row0 = (long)s * 128;
  const int lr = lane >> 3;
  const int sA = swz(lr, (lane & 7) * 8);

  // prefetch P tile to regs (T14 issue-early): thread: m=pm+i*32, t-seg pt0
  const int pm = tid >> 3, pt0 = (tid & 7) * 8;
  s16x8 pv[4];
  #pragma unroll
  for(int i = 0; i < 4; ++i)
    pv[i] = *(const s16x8*)&P[(row0 + pm + i * 32) * (long)PS + h * 64 + pt0];

  // scores[l][m] = sum_f Q[row0+l][f] * X[row0+m][f]  (K=768, dbuf loop)
  f32x4 acc[4][4] = {};
  auto stage = [&](int b, int kt){
    short* As = smem + b * 16384;
    #pragma unroll
    for(int it = 0; it < 4; ++it){
      int r = it * 32 + w * 8;
      gld_lds16(&Q[(row0 + r + lr) * (long)QS + hi * 768 + kt + sA], &As[r * 64]);
      gld_lds16(&X[(row0 + r + lr) * 768L + kt + sA], &As[8192 + r * 64]);
    }
  };

  stage(0, 0);
  for(int t = 0; t < 12; ++t){
    const int cur = t & 1;
    if(t < 11){
      stage(cur ^ 1, (t + 1) * 64);
      asm volatile("s_waitcnt vmcnt(8)\n\ts_barrier" ::: "memory");
    } else {
      asm volatile("s_waitcnt vmcnt(0)\n\ts_barrier" ::: "memory");
    }
    const short* As = smem + cur * 16384;
    const short* Bs = As + 8192;
    #pragma unroll
    for(int kk = 0; kk < 2; ++kk){
      s16x8 af[4], bfr[4];
      #pragma unroll
      for(int m = 0; m < 4; ++m){
        int row = wr * 64 + m * 16 + (lane & 15);
        af[m] = *(const s16x8*)&As[row * 64 + swz(row, kk * 32 + (lane >> 4) * 8)];
      }
      #pragma unroll
      for(int n = 0; n < 4; ++n){
        int row = wc * 64 + n * 16 + (lane & 15);
        bfr[n] = *(const s16x8*)&Bs[row * 64 + swz(row, kk * 32 + (lane >> 4) * 8)];
      }
      #pragma unroll
      for(int m = 0; m < 4; ++m)
        #pragma unroll
        for(int n = 0; n < 4; ++n)
          acc[m][n] = __builtin_amdgcn_mfma_f32_16x16x32_bf16(af[m], bfr[n], acc[m][n], 0, 0, 0);
    }
    asm volatile("s_barrier" ::: "memory");
  }

  // overlays on dead staging: Pt=As0 [64][128], Vt=Bs0 [128][64], Ss=As1|Bs1 [128][128]
  short* Pt = smem;
  short* Vt = smem + 8192;
  short* Ss = smem + 16384;

  #pragma unroll
  for(int m = 0; m < 4; ++m)
    #pragma unroll
    for(int n = 0; n < 4; ++n)
      #pragma unroll
      for(int r = 0; r < 4; ++r){
        int row = wr * 64 + m * 16 + (lane >> 4) * 4 + r;
        int c = wc * 64 + n * 16 + (lane & 15);
        Ss[row * 128 + (c ^ ((row & 7) * 8))] = f2bf(acc[m][n][r]);
      }
  #pragma unroll
  for(int i = 0; i < 4; ++i)
    #pragma unroll
    for(int j = 0; j < 8; ++j){
      int trow = pt0 + j;
      int mc = pm + i * 32;
      Pt[trow * 128 + (mc ^ ((trow & 7) * 8))] = pv[i][j];
    }
  __syncthreads();

  // V'[l][t] = sum_m Ss[l][m] * Pt[t][m]; wave w owns rows w*32..+31
  f32x4 accv[2][4] = {};
  #pragma unroll
  for(int kk = 0; kk < 4; ++kk){
    s16x8 a2[2], b4[4];
    #pragma unroll
    for(int m = 0; m < 2; ++m){
      int row = w * 32 + m * 16 + (lane & 15);
      a2[m] = *(const s16x8*)&Ss[row * 128 + ((kk * 32 + (lane >> 4) * 8) ^ ((row & 7) * 8))];
    }
    #pragma unroll
    for(int n = 0; n < 4; ++n){
      int trow = n * 16 + (lane & 15);
      b4[n] = *(const s16x8*)&Pt[trow * 128 + ((kk * 32 + (lane >> 4) * 8) ^ ((trow & 7) * 8))];
    }
    #pragma unroll
    for(int m = 0; m < 2; ++m)
      #pragma unroll
      for(int n = 0; n < 4; ++n)
        accv[m][n] = __builtin_amdgcn_mfma_f32_16x16x32_bf16(a2[m], b4[n], accv[m][n], 0, 0, 0);
  }

  // route V' through LDS for coalesced Cat stores
  #pragma unroll
  for(int m = 0; m < 2; ++m)
    #pragma unroll
    for(int n = 0; n < 4; ++n)
      #pragma unroll
      for(int r = 0; r < 4; ++r){
        int row = w * 32 + m * 16 + (lane >> 4) * 4 + r;
        int c = n * 16 + (lane & 15);
        Vt[row * 64 + (c ^ ((row & 7) * 8))] = f2bf(accv[m][n][r]);
      }
  __syncthreads();
  #pragma unroll
  for(int k2 = 0; k2 < 4; ++k2){
    int row = k2 * 32 + (tid >> 3);
    int cl = (tid & 7) * 8;
    s16x8 v = *(const s16x8*)&Vt[row * 64 + (cl ^ ((row & 7) * 8))];
    *(s16x8*)&Cat[(row0 + row) * 768L + h * 64 + cl] = v;
  }
}

extern "C" void kernel_launch(void* const* d_in, const int* in_sizes, int n_in,
                              void* d_out, int out_size, void* d_ws, size_t ws_size,
                              hipStream_t stream){
  const float* x  = (const float*)d_in[0];
  const float* Wq = (const float*)d_in[1];  // [12,768,768] = [9216,768]
  const float* bq = (const float*)d_in[2];  // [12,768] = [9216]
  const float* Wv = (const float*)d_in[3];  // [12,64,768] = [768,768]
  const float* bv = (const float*)d_in[4];
  const float* Wf = (const float*)d_in[5];
  const float* bfv= (const float*)d_in[6];

  const float rsqE = 0.03608439182435161f;  // 1/sqrt(768)
  char* ws = (char*)d_ws;
  const bool big = ws_size >= 1526507520ULL;  // one-shot QP GEMM path

  dim3 b256(256);
  if(big){
    short* Xb   = (short*)(ws + 0L);
    short* QP   = (short*)(ws + 100663296L);    // [65536][9984]
    short* Cat  = (short*)(ws + 1409286144L);   // [65536][768]
    short* Wb   = (short*)(ws + 1509949440L);   // [9984][768]
    short* Wfb  = (short*)(ws + 1525284864L);
    float* bQP  = (float*)(ws + 1526464512L);
    float* cv   = (float*)(ws + 1526504448L);

    cast_bf16_k<<<24576, b256, 0, stream>>>(x,  Xb, 50331648L, 1.f);
    cast_bf16_k<<<3456,  b256, 0, stream>>>(Wq, Wb, 7077888L, 1.f);
    cast_bf16_k<<<288,   b256, 0, stream>>>(Wv, Wb + 7077888L, 589824L, rsqE);
    cast_bf16_k<<<288,   b256, 0, stream>>>(Wf, Wfb, 589824L, 1.f);
    bias_build<<<39, b256, 0, stream>>>(bq, bQP);
    cvec_k<<<3, b256, 0, stream>>>(Wf, bv, bfv, cv);

    gemm_bt<false><<<dim3(39936), b256, 0, stream>>>(Xb, Wb, bQP, QP, 9984, 768);
    attn_k<<<dim3(6144), b256, 0, stream>>>(QP, 9984, QP + 9216, 9984, Xb, Cat, 0, 12);
    gemm_bt<true><<<dim3(3072), b256, 0, stream>>>(Cat, Wfb, cv, d_out, 768, 768);
  } else {
    short* Xb   = (short*)(ws + 0L);
    short* Pall = (short*)(ws + 100663296L);
    short* Qbuf = (short*)(ws + 201326592L);
    short* Cat  = (short*)(ws + 301989888L);
    short* Wb   = (short*)(ws + 402653184L);    // [9984][768]
    short* Wfb  = (short*)(ws + 417988608L);
    float* bQP  = (float*)(ws + 419168256L);
    float* cv   = (float*)(ws + 419208192L);

    cast_bf16_k<<<24576, b256, 0, stream>>>(x,  Xb, 50331648L, 1.f);
    cast_bf16_k<<<3456,  b256, 0, stream>>>(Wq, Wb, 7077888L, 1.f);
    cast_bf16_k<<<288,   b256, 0, stream>>>(Wv, Wb + 7077888L, 589824L, rsqE);
    cast_bf16_k<<<288,   b256, 0, stream>>>(Wf, Wfb, 589824L, 1.f);
    bias_build<<<39, b256, 0, stream>>>(bq, bQP);
    cvec_k<<<3, b256, 0, stream>>>(Wf, bv, bfv, cv);

    // P = Xb @ (Wv*rsqE)^T
    gemm_bt<false><<<dim3(3072), b256, 0, stream>>>(Xb, Wb + 7077888L, nullptr, Pall, 768, 768);
    for(int h = 0; h < 12; ++h){
      gemm_bt<false><<<dim3(3072), b256, 0, stream>>>(Xb, Wb + (long)h * 589824L,
                                                      bQP + h * 768, Qbuf, 768, 768);
      attn_k<<<dim3(512), b256, 0, stream>>>(Qbuf, 768, Pall, 768, Xb, Cat, h, 1);
    }
    gemm_bt<true><<<dim3(3072), b256, 0, stream>>>(Cat, Wfb, cv, d_out, 768, 768);
  }
}

// Round 4
// 1739.654 us; speedup vs baseline: 1.3977x; 1.0674x over previous
//
#include <hip/hip_runtime.h>
#include <stdint.h>

// SelfAttention: B=64,N=8,L=128,E=768,H=12,T=64  (S=512 sets of 128 tokens)
//
// Pipeline (bf16 MFMA, fp32 accum):
//   Xb = bf16(x)                                   [65536,768]
//   Q_h = Xb @ Wq[h]^T + bq[h], P = Xb @ (Wv/√E)^T — batched 256² GEMMs
//   attn per (h,s): scores = Q[h,s]@Xs^T ; V' = scores@P[h,s] -> Cat
//   out = Cat @ Wf^T + (bf + Wf@bv)                [65536,768] fp32
//
// gemm256: 256x256 tile, BK=32, 8 waves, 64KB LDS dbuf, counted vmcnt(4)
// (never drains mid-loop), 4 quadrant sub-phases with setprio, swizzled LDS
// (inverse-on-source / forward-on-read), XCD-chunked grid, zero-tail grids.

#define EE 768
#define SLOT 50331648L   // shorts per [65536][768] slot

typedef short s16x8 __attribute__((ext_vector_type(8)));
typedef float f32x4 __attribute__((ext_vector_type(4)));

__device__ __forceinline__ short f2bf(float f){
  union { float fv; uint32_t u; } v; v.fv = f;
  uint32_t r = (v.u + 0x7fffu + ((v.u >> 16) & 1u)) >> 16;  // RNE
  return (short)r;
}

__device__ __forceinline__ void gld_lds16(const short* g, short* l){
  __builtin_amdgcn_global_load_lds(
      (const __attribute__((address_space(1))) void*)(uintptr_t)g,
      (__attribute__((address_space(3))) void*)(uintptr_t)l,
      16, 0, 0);
}

// bijective XCD chunking (m204)
__device__ __forceinline__ int xcd_swz(int bid, int nwg){
  int xcd = bid & 7, loc = bid >> 3;
  int q = nwg >> 3, r = nwg & 7;
  return (xcd < r ? xcd * (q + 1) : r * (q + 1) + (xcd - r) * q) + loc;
}

// swizzles (involutions)
__device__ __forceinline__ int swz64(int row, int c){ return c ^ ((row & 7) << 3); }   // 64-col tiles
__device__ __forceinline__ int swz32(int row, int c){ return c ^ (((row >> 1) & 3) << 3); } // 32-col tiles

// ---------------- casts / small helpers ----------------
__global__ __launch_bounds__(256) void cast_bf16_k(const float* __restrict__ src,
                                                   short* __restrict__ dst,
                                                   long n, float scale){
  long i = ((long)blockIdx.x * 256 + threadIdx.x) * 8;
  if(i >= n) return;
  float4 a = *(const float4*)(src + i);
  float4 b = *(const float4*)(src + i + 4);
  s16x8 o;
  o[0]=f2bf(a.x*scale); o[1]=f2bf(a.y*scale); o[2]=f2bf(a.z*scale); o[3]=f2bf(a.w*scale);
  o[4]=f2bf(b.x*scale); o[5]=f2bf(b.y*scale); o[6]=f2bf(b.z*scale); o[7]=f2bf(b.w*scale);
  *(s16x8*)(dst + i) = o;
}

__global__ __launch_bounds__(256) void cvec_k(const float* __restrict__ Wf,
                                              const float* __restrict__ bv,
                                              const float* __restrict__ bfv,
                                              float* __restrict__ c){
  int e = blockIdx.x * 256 + threadIdx.x;
  if(e >= EE) return;
  float s = bfv[e];
  for(int k = 0; k < EE; ++k) s += Wf[(long)e * EE + k] * bv[k];
  c[e] = s;
}

__global__ __launch_bounds__(256) void bias_build(const float* __restrict__ bq,
                                                  float* __restrict__ biasQP){
  int i = blockIdx.x * 256 + threadIdx.x;
  if(i < 9984) biasQP[i] = (i < 9216) ? bq[i] : 0.f;
}

// ---------- batched 256x256 projection GEMM: Out[g] = Xb @ W[wh]^T + bias ----------
// grid = nSub*768 blocks of 512 threads; 1 block/CU; sub g: weight head wh,
// output slot g. rowBlk 0..255, colBlk 0..2.
__global__ __launch_bounds__(512, 1) void gemm256(const short* __restrict__ A,
                                                  const short* __restrict__ W,
                                                  const float* __restrict__ bias,
                                                  short* __restrict__ OutBase,
                                                  int hBase, int nSub, int pSub){
  __shared__ short lds[2][16384];   // [buf][A 8192 | B 8192]
  const int tid = threadIdx.x, lane = tid & 63, w = tid >> 6;
  const int wr = w >> 2, wc = w & 3;
  const int bid = xcd_swz(blockIdx.x, nSub * 768);
  const int g = bid / 768, rb = bid - g * 768;
  const int rowBlk = rb / 3, colBlk = rb - rowBlk * 3;
  const long rowA0 = (long)rowBlk * 256;
  const int colB0 = colBlk * 256;
  const int wh = (g == pSub) ? 12 : hBase + g;
  const short* Bm = W + (long)wh * 589824L;
  short* Out = OutBase + (long)g * SLOT;

  // staging: wave w instr j covers LDS rows [(w*2+j)*16,+16); lane: row +lane>>2,
  // col (lane&3)*8. Source col pre-inverse-swizzled.
  const int sr0 = w * 32 + (lane >> 2);
  const int sr1 = sr0 + 16;
  const int scol = (lane & 3) * 8;
  const int sc0 = swz32(sr0, scol);
  const int sc1 = swz32(sr1, scol);
  const short* Ar0 = A + (rowA0 + sr0) * 768;
  const short* Ar1 = A + (rowA0 + sr1) * 768;
  const short* Br0 = Bm + (long)(colB0 + sr0) * 768;
  const short* Br1 = Bm + (long)(colB0 + sr1) * 768;

  f32x4 acc[8][4] = {};
  s16x8 af[4], bf0[2], bf1[2];
  const int fr = lane & 15, fc = (lane >> 4) * 8;

  auto stage = [&](int b, int kt){
    short* Al = &lds[b][0];
    short* Bl = &lds[b][8192];
    gld_lds16(Ar0 + kt + sc0, Al + (w * 2) * 512);
    gld_lds16(Ar1 + kt + sc1, Al + (w * 2 + 1) * 512);
    gld_lds16(Br0 + kt + sc0, Bl + (w * 2) * 512);
    gld_lds16(Br1 + kt + sc1, Bl + (w * 2 + 1) * 512);
  };

  stage(0, 0);
  for(int t = 0; t < 24; ++t){
    if(t < 23){
      stage((t + 1) & 1, (t + 1) * 32);
      asm volatile("s_waitcnt vmcnt(4)\n\ts_barrier" ::: "memory");
    } else {
      asm volatile("s_waitcnt vmcnt(0)\n\ts_barrier" ::: "memory");
    }
    const short* Al = &lds[t & 1][0];
    const short* Bl = &lds[t & 1][8192];

    auto loadA = [&](int mh){
      #pragma unroll
      for(int m = 0; m < 4; ++m){
        int row = wr * 128 + (mh * 4 + m) * 16 + fr;
        af[m] = *(const s16x8*)&Al[row * 32 + swz32(row, fc)];
      }
    };
    auto loadB = [&](int nh, s16x8* bf){
      #pragma unroll
      for(int n = 0; n < 2; ++n){
        int row = wc * 64 + (nh * 2 + n) * 16 + fr;
        bf[n] = *(const s16x8*)&Bl[row * 32 + swz32(row, fc)];
      }
    };
    auto mm = [&](int mh, int nh, s16x8* bf){
      __builtin_amdgcn_s_setprio(1);
      #pragma unroll
      for(int m = 0; m < 4; ++m)
        #pragma unroll
        for(int n = 0; n < 2; ++n)
          acc[mh * 4 + m][nh * 2 + n] = __builtin_amdgcn_mfma_f32_16x16x32_bf16(
              af[m], bf[n], acc[mh * 4 + m][nh * 2 + n], 0, 0, 0);
      __builtin_amdgcn_s_setprio(0);
    };

    loadA(0); loadB(0, bf0); mm(0, 0, bf0);
    loadB(1, bf1);           mm(0, 1, bf1);
    loadA(1);                mm(1, 1, bf1);
    loadB(0, bf0);           mm(1, 0, bf0);
    asm volatile("s_barrier" ::: "memory");
  }

  // epilogue: per 128-row chunk, route through LDS for coalesced 256B stores
  float bb[4];
  #pragma unroll
  for(int n = 0; n < 4; ++n)
    bb[n] = bias[wh * 768 + colB0 + wc * 64 + n * 16 + fr];

  short* Cs = &lds[0][0];  // [128][256]
  #pragma unroll
  for(int ch = 0; ch < 2; ++ch){
    __syncthreads();
    if(wr == ch){
      #pragma unroll
      for(int m = 0; m < 8; ++m)
        #pragma unroll
        for(int n = 0; n < 4; ++n)
          #pragma unroll
          for(int r2 = 0; r2 < 4; ++r2){
            int row = m * 16 + (lane >> 4) * 4 + r2;
            int c = wc * 64 + n * 16 + fr;
            Cs[row * 256 + (c ^ (((row >> 2) & 3) << 4))] = f2bf(acc[m][n][r2] + bb[n]);
          }
    }
    __syncthreads();
    #pragma unroll
    for(int i = 0; i < 8; ++i){
      int idx = i * 512 + tid;
      int row = idx >> 5, cl = (idx & 31) * 8;
      s16x8 v = *(const s16x8*)&Cs[row * 256 + (cl ^ (((row >> 2) & 3) << 4))];
      *(s16x8*)&Out[(rowA0 + ch * 128 + row) * 768 + colB0 + cl] = v;
    }
  }
}

// ------ final C[M,768] = A @ B^T + bias (fp32 out); 128² 2-phase (proven) ------
__global__ __launch_bounds__(256, 2) void gemm_f32(const short* __restrict__ A,
                                                   const short* __restrict__ B,
                                                   const float* __restrict__ bias,
                                                   float* __restrict__ Cout){
  __shared__ short smem[4 * 8192];
  const int tid = threadIdx.x, lane = tid & 63, w = tid >> 6;
  const int wr = w >> 1, wc = w & 1;
  const int nCol = 6;
  const int xcd = blockIdx.x & 7, loc = blockIdx.x >> 3;
  const int width = nCol << 3;
  const int gid = loc / width, rem = loc % width;
  const int rowBlk = (xcd << 6) + (gid << 3) + (rem & 7);
  const int colBlk = rem >> 3;
  const long rowA0 = (long)rowBlk << 7;
  const long colB0 = (long)colBlk << 7;
  const int lr = lane >> 3;
  const int sA = swz64(lr, (lane & 7) * 8);

  f32x4 acc[4][4] = {};
  auto stage = [&](int b, int kt){
    short* As = smem + b * 16384;
    #pragma unroll
    for(int it = 0; it < 4; ++it){
      int r = it * 32 + w * 8;
      gld_lds16(&A[(rowA0 + r + lr) * 768 + kt + sA], &As[r * 64]);
      gld_lds16(&B[(colB0 + r + lr) * 768 + kt + sA], &As[8192 + r * 64]);
    }
  };

  stage(0, 0);
  for(int t = 0; t < 12; ++t){
    const int cur = t & 1;
    if(t < 11){
      stage(cur ^ 1, (t + 1) * 64);
      asm volatile("s_waitcnt vmcnt(8)\n\ts_barrier" ::: "memory");
    } else {
      asm volatile("s_waitcnt vmcnt(0)\n\ts_barrier" ::: "memory");
    }
    const short* As = smem + cur * 16384;
    const short* Bs = As + 8192;
    #pragma unroll
    for(int kk = 0; kk < 2; ++kk){
      s16x8 af[4], bfr[4];
      #pragma unroll
      for(int m = 0; m < 4; ++m){
        int row = wr * 64 + m * 16 + (lane & 15);
        af[m] = *(const s16x8*)&As[row * 64 + swz64(row, kk * 32 + (lane >> 4) * 8)];
      }
      #pragma unroll
      for(int n = 0; n < 4; ++n){
        int row = wc * 64 + n * 16 + (lane & 15);
        bfr[n] = *(const s16x8*)&Bs[row * 64 + swz64(row, kk * 32 + (lane >> 4) * 8)];
      }
      #pragma unroll
      for(int m = 0; m < 4; ++m)
        #pragma unroll
        for(int n = 0; n < 4; ++n)
          acc[m][n] = __builtin_amdgcn_mfma_f32_16x16x32_bf16(af[m], bfr[n], acc[m][n], 0, 0, 0);
    }
    asm volatile("s_barrier" ::: "memory");
  }

  const long crow0 = rowA0 + wr * 64;
  const long ccol0 = colB0 + wc * 64;
  #pragma unroll
  for(int n = 0; n < 4; ++n){
    const long col = ccol0 + n * 16 + (lane & 15);
    const float bbv = bias[col];
    #pragma unroll
    for(int m = 0; m < 4; ++m)
      #pragma unroll
      for(int r = 0; r < 4; ++r){
        const long row = crow0 + m * 16 + (lane >> 4) * 4 + r;
        Cout[row * 768 + col] = acc[m][n][r] + bbv;
      }
  }
}

// ------ fused per-(h,s): scores = Q@Xs^T ; V' = scores@P ; -> Cat -----------
__global__ __launch_bounds__(256, 2) void attn_k(const short* __restrict__ Q,
                                                 const short* __restrict__ P,
                                                 const short* __restrict__ X,
                                                 short* __restrict__ Cat,
                                                 int h0, int nH){
  __shared__ short smem[4 * 8192];
  const int tid = threadIdx.x, lane = tid & 63, w = tid >> 6;
  const int wr = w >> 1, wc = w & 1;
  const int nwg = nH << 9;
  const int bid = xcd_swz(blockIdx.x, nwg);
  const int s = bid / nH, hi = bid - s * nH, h = h0 + hi;
  const long row0 = (long)s * 128;
  const int lr = lane >> 3;
  const int sA = swz64(lr, (lane & 7) * 8);

  // prefetch P tile to regs
  const int pm = tid >> 3, pt0 = (tid & 7) * 8;
  s16x8 pv[4];
  #pragma unroll
  for(int i = 0; i < 4; ++i)
    pv[i] = *(const s16x8*)&P[(row0 + pm + i * 32) * 768L + h * 64 + pt0];

  f32x4 acc[4][4] = {};
  const short* Qh = Q + (long)hi * SLOT;
  auto stage = [&](int b, int kt){
    short* As = smem + b * 16384;
    #pragma unroll
    for(int it = 0; it < 4; ++it){
      int r = it * 32 + w * 8;
      gld_lds16(&Qh[(row0 + r + lr) * 768L + kt + sA], &As[r * 64]);
      gld_lds16(&X[(row0 + r + lr) * 768L + kt + sA], &As[8192 + r * 64]);
    }
  };

  stage(0, 0);
  for(int t = 0; t < 12; ++t){
    const int cur = t & 1;
    if(t < 11){
      stage(cur ^ 1, (t + 1) * 64);
      asm volatile("s_waitcnt vmcnt(8)\n\ts_barrier" ::: "memory");
    } else {
      asm volatile("s_waitcnt vmcnt(0)\n\ts_barrier" ::: "memory");
    }
    const short* As = smem + cur * 16384;
    const short* Bs = As + 8192;
    #pragma unroll
    for(int kk = 0; kk < 2; ++kk){
      s16x8 af[4], bfr[4];
      #pragma unroll
      for(int m = 0; m < 4; ++m){
        int row = wr * 64 + m * 16 + (lane & 15);
        af[m] = *(const s16x8*)&As[row * 64 + swz64(row, kk * 32 + (lane >> 4) * 8)];
      }
      #pragma unroll
      for(int n = 0; n < 4; ++n){
        int row = wc * 64 + n * 16 + (lane & 15);
        bfr[n] = *(const s16x8*)&Bs[row * 64 + swz64(row, kk * 32 + (lane >> 4) * 8)];
      }
      #pragma unroll
      for(int m = 0; m < 4; ++m)
        #pragma unroll
        for(int n = 0; n < 4; ++n)
          acc[m][n] = __builtin_amdgcn_mfma_f32_16x16x32_bf16(af[m], bfr[n], acc[m][n], 0, 0, 0);
    }
    asm volatile("s_barrier" ::: "memory");
  }

  short* Pt = smem;           // [64][128]
  short* Vt = smem + 8192;    // [128][64]
  short* Ss = smem + 16384;   // [128][128]

  #pragma unroll
  for(int m = 0; m < 4; ++m)
    #pragma unroll
    for(int n = 0; n < 4; ++n)
      #pragma unroll
      for(int r = 0; r < 4; ++r){
        int row = wr * 64 + m * 16 + (lane >> 4) * 4 + r;
        int c = wc * 64 + n * 16 + (lane & 15);
        Ss[row * 128 + swz64(row, c)] = f2bf(acc[m][n][r]);
      }
  #pragma unroll
  for(int i = 0; i < 4; ++i)
    #pragma unroll
    for(int j = 0; j < 8; ++j){
      int trow = pt0 + j;
      int mc = pm + i * 32;
      Pt[trow * 128 + swz64(trow, mc)] = pv[i][j];
    }
  __syncthreads();

  f32x4 accv[2][4] = {};
  #pragma unroll
  for(int kk = 0; kk < 4; ++kk){
    s16x8 a2[2], b4[4];
    #pragma unroll
    for(int m = 0; m < 2; ++m){
      int row = w * 32 + m * 16 + (lane & 15);
      a2[m] = *(const s16x8*)&Ss[row * 128 + swz64(row, kk * 32 + (lane >> 4) * 8)];
    }
    #pragma unroll
    for(int n = 0; n < 4; ++n){
      int trow = n * 16 + (lane & 15);
      b4[n] = *(const s16x8*)&Pt[trow * 128 + swz64(trow, kk * 32 + (lane >> 4) * 8)];
    }
    #pragma unroll
    for(int m = 0; m < 2; ++m)
      #pragma unroll
      for(int n = 0; n < 4; ++n)
        accv[m][n] = __builtin_amdgcn_mfma_f32_16x16x32_bf16(a2[m], b4[n], accv[m][n], 0, 0, 0);
  }

  #pragma unroll
  for(int m = 0; m < 2; ++m)
    #pragma unroll
    for(int n = 0; n < 4; ++n)
      #pragma unroll
      for(int r = 0; r < 4; ++r){
        int row = w * 32 + m * 16 + (lane >> 4) * 4 + r;
        int c = n * 16 + (lane & 15);
        Vt[row * 64 + swz64(row, c)] = f2bf(accv[m][n][r]);
      }
  __syncthreads();
  #pragma unroll
  for(int k2 = 0; k2 < 4; ++k2){
    int row = k2 * 32 + (tid >> 3);
    int cl = (tid & 7) * 8;
    s16x8 v = *(const s16x8*)&Vt[row * 64 + swz64(row, cl)];
    *(s16x8*)&Cat[(row0 + row) * 768L + h * 64 + cl] = v;
  }
}

extern "C" void kernel_launch(void* const* d_in, const int* in_sizes, int n_in,
                              void* d_out, int out_size, void* d_ws, size_t ws_size,
                              hipStream_t stream){
  const float* x  = (const float*)d_in[0];
  const float* Wq = (const float*)d_in[1];
  const float* bq = (const float*)d_in[2];
  const float* Wv = (const float*)d_in[3];
  const float* bv = (const float*)d_in[4];
  const float* Wf = (const float*)d_in[5];
  const float* bfv= (const float*)d_in[6];

  const float rsqE = 0.03608439182435161f;  // 1/sqrt(768)
  char* ws = (char*)d_ws;

  // layout (bytes)
  short* Xb  = (short*)(ws);
  short* Cat = (short*)(ws + 100663296L);
  short* Wb  = (short*)(ws + 201326592L);   // [13*768][768] bf16
  short* Wfb = (short*)(ws + 216662016L);
  float* bQP = (float*)(ws + 217841664L);   // [9984]
  float* cv  = (float*)(ws + 217881600L);
  short* QS  = (short*)(ws + 217884672L);   // (G+1) slots of [65536][768]

  const size_t QOFF = 217884672ULL;
  int G = 1;
  const int cands[5] = {12, 6, 4, 3, 2};
  for(int i = 0; i < 5; ++i)
    if(ws_size >= QOFF + (size_t)(cands[i] + 1) * 100663296ULL){ G = cands[i]; break; }
  short* Pall = QS + (long)G * SLOT;

  dim3 b256(256), b512(512);
  cast_bf16_k<<<24576, b256, 0, stream>>>(x,  Xb, 50331648L, 1.f);
  cast_bf16_k<<<3456,  b256, 0, stream>>>(Wq, Wb, 7077888L, 1.f);
  cast_bf16_k<<<288,   b256, 0, stream>>>(Wv, Wb + 7077888L, 589824L, rsqE);
  cast_bf16_k<<<288,   b256, 0, stream>>>(Wf, Wfb, 589824L, 1.f);
  bias_build<<<39, b256, 0, stream>>>(bq, bQP);
  cvec_k<<<3, b256, 0, stream>>>(Wf, bv, bfv, cv);

  const int nB = 12 / G;
  for(int b = 0; b < nB; ++b){
    const int nSub = G + (b == 0 ? 1 : 0);
    const int pSub = (b == 0) ? G : -1;
    gemm256<<<dim3(nSub * 768), b512, 0, stream>>>(Xb, Wb, bQP, QS, b * G, nSub, pSub);
    attn_k<<<dim3(G * 512), b256, 0, stream>>>(QS, Pall, Xb, Cat, b * G, G);
  }
  gemm_f32<<<dim3(3072), b256, 0, stream>>>(Cat, Wfb, cv, (float*)d_out);
}